// Round 8
// baseline (5960.328 us; speedup 1.0000x reference)
//
#include <hip/hip_runtime.h>

// HSMM forward log-likelihood, B=32, T=8192, K=128, Dmax=128.
// One block per sequence; R8: 4 waves (256 threads), 2 states per thread.
// Probability-space recursion, per-state gauge psi (write-once ring slots),
// 1-step-delayed renorm by a block-uniform proxy max (wave 0's 32 states) --
// any positive block-uniform scalar is an exact gauge; clamp is the firewall.
//
// Lane layout (per wave): c = L&3 (source chunk, quad lanes), jl = L>>2.
// States: jj0 = jl + 16w (0..63), jj1 = jj0 + 64.  Per state: ring QA/QB[16]
// (slots 32c+k / 32c+16+k), rotating expD window eA/eB[16], expA aA/aB[16],
// logB prefetch ring lb[16] (16 steps ahead, global loads stay in flight
// across the no-vmcnt-drain barrier).
//
// vs R6 (verified, 5361us): half the waves (half the LDS queue + cheaper
// barrier), gauge-lite (1 b32 proxy max instead of 2 b128 + 7-max tree per
// wave), xor-skewed expD table (kills the 4-way rotation-read conflicts).

#define T_LEN 8192
#define KST   128
#define NTHR  256
#define SROW  160   // skewed shat row: addr(j) = j + 8*(j>>5) <= 151 < 160

__device__ __forceinline__ void barrier_nodrain() {
  asm volatile("s_waitcnt lgkmcnt(0)\n\ts_barrier" ::: "memory");
}

// DPP move: result = src permuted by CTRL; invalid lanes -> 0 (bound_ctrl).
template <int CTRL>
__device__ __forceinline__ float dpp_mov(float x) {
  int y = __builtin_amdgcn_update_dpp(0, __builtin_bit_cast(int, x),
                                      CTRL, 0xF, 0xF, true);
  return __builtin_bit_cast(float, y);
}
template <int CTRL>
__device__ __forceinline__ float dpp_add(float x) { return x + dpp_mov<CTRL>(x); }

template <int U>
__device__ __forceinline__ void step_body(
    int t0, int c, int jj0, int jj1, int w, int L,
    const float* __restrict__ pB0, const float* __restrict__ pB1,
    float (&QA0)[16], float (&QB0)[16], float (&QA1)[16], float (&QB1)[16],
    const float (&aA0)[16], const float (&aB0)[16],
    const float (&aA1)[16], const float (&aB1)[16],
    float (&eA0)[16], float (&eB0)[16], float (&eA1)[16], float (&eB1)[16],
    float (&lb0)[16], float (&lb1)[16],
    float& psi0, float& psi1, float& invpsi0, float& invpsi1,
    float& exq0, float& exq1, float& Ctot, float& sk0, float& sk1,
    float expD00, float expD01, float pexp0, float pexp1,
    int saddr0, int saddr1,
    float (*s_lds)[SROW], float* m_sc,
    const float (*expD_x)[KST])
{
  const int t = t0 + U;
  const float expB0 = exq0, expB1 = exq1;  // exp(logB[t,j]), computed last step

  // (a) prefetch logB t+16 (vmcnt; stays in flight across barriers)
  int tn = t + 16; tn = (tn < T_LEN) ? tn : (T_LEN - 1);
  lb0[U] = pB0[(size_t)tn * KST];
  lb1[U] = pB1[(size_t)tn * KST];

  // (b) expD rotation reads for NEXT step (xor-skewed cols; temps)
  const int rowA = (t + 1 - 32 * c) & 127;
  const int rowB = (rowA - 16) & 127;
  const int skA = (rowA & 96) >> 2, skB = (rowB & 96) >> 2;
  const float neA0 = expD_x[rowA][jj0 ^ skA];
  const float neB0 = expD_x[rowB][jj0 ^ skB];
  const float neA1 = expD_x[rowA][jj1 ^ skA];
  const float neB1 = expD_x[rowB][jj1 ^ skB];

  // (c) gauge scalar from step t-1 (1 b32 broadcast; exact free gauge)
  float Mp = m_sc[U & 1];
  Mp = fminf(fmaxf(Mp, 1e-30f), 1e30f);
  const float rMp = __builtin_amdgcn_rcpf(Mp);

  // (d) shat(t-1): this chunk's 32 states (8 b128, 4 bank-disjoint addr sets)
  const float* sp = &s_lds[U & 1][40 * c];
  const float4 s0 = *(const float4*)(sp + 0),  s1 = *(const float4*)(sp + 4);
  const float4 s2 = *(const float4*)(sp + 8),  s3 = *(const float4*)(sp + 12);
  const float4 s4 = *(const float4*)(sp + 16), s5 = *(const float4*)(sp + 20);
  const float4 s6 = *(const float4*)(sp + 24), s7 = *(const float4*)(sp + 28);

  // (e) duration dots: register-only, 4 accs per state
  float d0 = 0.f, d1 = 0.f, d2 = 0.f, d3 = 0.f;
  float g0 = 0.f, g1 = 0.f, g2 = 0.f, g3 = 0.f;
#pragma unroll
  for (int k = 0; k < 8; ++k) {
    d0 = fmaf(QA0[k],     eA0[(k - U) & 15],     d0);
    d1 = fmaf(QA0[k + 8], eA0[(k + 8 - U) & 15], d1);
    d2 = fmaf(QB0[k],     eB0[(k - U) & 15],     d2);
    d3 = fmaf(QB0[k + 8], eB0[(k + 8 - U) & 15], d3);
    g0 = fmaf(QA1[k],     eA1[(k - U) & 15],     g0);
    g1 = fmaf(QA1[k + 8], eA1[(k + 8 - U) & 15], g1);
    g2 = fmaf(QB1[k],     eB1[(k - U) & 15],     g2);
    g3 = fmaf(QB1[k + 8], eB1[(k + 8 - U) & 15], g3);
  }
  float dp0 = (d0 + d1) + (d2 + d3);
  float dp1 = (g0 + g1) + (g2 + g3);

  // (f) gauge update (per state)
  Ctot += __logf(Mp);
  psi0 = psi0 * expB0 * rMp;
  psi1 = psi1 * expB1 * rMp;

  // (g) matvec partials over this chunk's 32 sources, both dests
  float m0 = 0.f, m1 = 0.f, m2 = 0.f, m3 = 0.f;
  float n0 = 0.f, n1 = 0.f, n2 = 0.f, n3 = 0.f;
  m0 = fmaf(aA0[0],  s0.x, m0); m0 = fmaf(aA0[1],  s0.y, m0);
  m0 = fmaf(aA0[2],  s0.z, m0); m0 = fmaf(aA0[3],  s0.w, m0);
  m0 = fmaf(aA0[4],  s1.x, m0); m0 = fmaf(aA0[5],  s1.y, m0);
  m0 = fmaf(aA0[6],  s1.z, m0); m0 = fmaf(aA0[7],  s1.w, m0);
  m1 = fmaf(aA0[8],  s2.x, m1); m1 = fmaf(aA0[9],  s2.y, m1);
  m1 = fmaf(aA0[10], s2.z, m1); m1 = fmaf(aA0[11], s2.w, m1);
  m1 = fmaf(aA0[12], s3.x, m1); m1 = fmaf(aA0[13], s3.y, m1);
  m1 = fmaf(aA0[14], s3.z, m1); m1 = fmaf(aA0[15], s3.w, m1);
  m2 = fmaf(aB0[0],  s4.x, m2); m2 = fmaf(aB0[1],  s4.y, m2);
  m2 = fmaf(aB0[2],  s4.z, m2); m2 = fmaf(aB0[3],  s4.w, m2);
  m2 = fmaf(aB0[4],  s5.x, m2); m2 = fmaf(aB0[5],  s5.y, m2);
  m2 = fmaf(aB0[6],  s5.z, m2); m2 = fmaf(aB0[7],  s5.w, m2);
  m3 = fmaf(aB0[8],  s6.x, m3); m3 = fmaf(aB0[9],  s6.y, m3);
  m3 = fmaf(aB0[10], s6.z, m3); m3 = fmaf(aB0[11], s6.w, m3);
  m3 = fmaf(aB0[12], s7.x, m3); m3 = fmaf(aB0[13], s7.y, m3);
  m3 = fmaf(aB0[14], s7.z, m3); m3 = fmaf(aB0[15], s7.w, m3);
  n0 = fmaf(aA1[0],  s0.x, n0); n0 = fmaf(aA1[1],  s0.y, n0);
  n0 = fmaf(aA1[2],  s0.z, n0); n0 = fmaf(aA1[3],  s0.w, n0);
  n0 = fmaf(aA1[4],  s1.x, n0); n0 = fmaf(aA1[5],  s1.y, n0);
  n0 = fmaf(aA1[6],  s1.z, n0); n0 = fmaf(aA1[7],  s1.w, n0);
  n1 = fmaf(aA1[8],  s2.x, n1); n1 = fmaf(aA1[9],  s2.y, n1);
  n1 = fmaf(aA1[10], s2.z, n1); n1 = fmaf(aA1[11], s2.w, n1);
  n1 = fmaf(aA1[12], s3.x, n1); n1 = fmaf(aA1[13], s3.y, n1);
  n1 = fmaf(aA1[14], s3.z, n1); n1 = fmaf(aA1[15], s3.w, n1);
  n2 = fmaf(aB1[0],  s4.x, n2); n2 = fmaf(aB1[1],  s4.y, n2);
  n2 = fmaf(aB1[2],  s4.z, n2); n2 = fmaf(aB1[3],  s4.w, n2);
  n2 = fmaf(aB1[4],  s5.x, n2); n2 = fmaf(aB1[5],  s5.y, n2);
  n2 = fmaf(aB1[6],  s5.z, n2); n2 = fmaf(aB1[7],  s5.w, n2);
  n3 = fmaf(aB1[8],  s6.x, n3); n3 = fmaf(aB1[9],  s6.y, n3);
  n3 = fmaf(aB1[10], s6.z, n3); n3 = fmaf(aB1[11], s6.w, n3);
  n3 = fmaf(aB1[12], s7.x, n3); n3 = fmaf(aB1[13], s7.y, n3);
  n3 = fmaf(aB1[14], s7.z, n3); n3 = fmaf(aB1[15], s7.w, n3);
  float mp0 = (m0 + m1) + (m2 + m3);
  float mp1 = (n0 + n1) + (n2 + n3);

  // (h) quad reduce (lane bits 0,1): DPP butterflies
  dp0 = dpp_add<0xB1>(dp0); dp0 = dpp_add<0x4E>(dp0);
  dp1 = dpp_add<0xB1>(dp1); dp1 = dpp_add<0x4E>(dp1);
  mp0 = dpp_add<0xB1>(mp0); mp0 = dpp_add<0x4E>(mp0);
  mp1 = dpp_add<0xB1>(mp1); mp1 = dpp_add<0x4E>(mp1);

  // (i) insert values (M cancels exactly); shat (quad-uniform)
  const float Qins0 = (t == 0) ? pexp0 : mp0 * invpsi0;
  const float Qins1 = (t == 0) ? pexp1 : mp1 * invpsi1;
  const float sv0 = fmaf(Qins0, expD00, dp0) * psi0;
  const float sv1 = fmaf(Qins1, expD01, dp1) * psi1;

  // (j) exp for NEXT step (loaded 15 steps ago -> arrived)
  exq0 = __expf(lb0[(U + 1) & 15]);
  exq1 = __expf(lb1[(U + 1) & 15]);

  // (k) ring insert: slot p = t&127 -> quarter (t>>5)&3, half bit4, reg U
  const bool mine = (((t >> 5) & 3) == c);
  if ((t >> 4) & 1) {
    if (mine) { QB0[U] = Qins0; QB1[U] = Qins1; }
  } else {
    if (mine) { QA0[U] = Qins0; QA1[U] = Qins1; }
  }

  // (l) gauge proxy max: wave 0 only (32 states), R6-verified DPP chain
  if (w == 0) {
    float sm = fmaxf(sv0, sv1);
    sm = fmaxf(sm, dpp_mov<0x141>(sm));
    sm = fmaxf(sm, dpp_mov<0x140>(sm));
    sm = fmaxf(sm, dpp_mov<0x142>(sm));
    sm = fmaxf(sm, dpp_mov<0x143>(sm));
    if (L == 63) m_sc[(U + 1) & 1] = sm;
  }

  // (m) publish shat (one lane per state), skewed conflict-free
  if (c == 0) {
    s_lds[(U + 1) & 1][saddr0] = sv0;
    s_lds[(U + 1) & 1][saddr1] = sv1;
  }

  // (n) commit expD window rotation (old values fully consumed in (e))
  eA0[(15 - U) & 15] = neA0;  eB0[(15 - U) & 15] = neB0;
  eA1[(15 - U) & 15] = neA1;  eB1[(15 - U) & 15] = neB1;

  // (o) gauge renorm every 16 steps: fold psi into ring, reset
  if (U == 15) {
#pragma unroll
    for (int k = 0; k < 16; ++k) {
      QA0[k] *= psi0; QB0[k] *= psi0;
      QA1[k] *= psi1; QB1[k] *= psi1;
    }
    psi0 = 1.0f; psi1 = 1.0f;
  }

  // (p) 1/psi for next step (off-path)
  invpsi0 = __builtin_amdgcn_rcpf(psi0);
  invpsi1 = __builtin_amdgcn_rcpf(psi1);

  sk0 = sv0; sk1 = sv1;
  barrier_nodrain();
}

__global__ __launch_bounds__(NTHR, 1) void hsmm_fwd_kernel(
    const float* __restrict__ logB_all,
    const float* __restrict__ logpi,
    const float* __restrict__ logA,
    const float* __restrict__ logD,
    float* __restrict__ out)
{
  const int tid = threadIdx.x;
  const int L   = tid & 63;
  const int w   = tid >> 6;          // 0..3
  const int c   = L & 3;             // source chunk (quad lanes)
  const int jl  = L >> 2;            // 0..15
  const int jj0 = jl + 16 * w;       // state 0 (0..63)
  const int jj1 = jj0 + 64;          // state 1 (64..127)
  const int b   = blockIdx.x;
  const float* __restrict__ pB0 = logB_all + (size_t)b * T_LEN * KST + jj0;
  const float* __restrict__ pB1 = pB0 + 64;

  __shared__ __align__(16) float expD_x[128][KST]; // [d][j ^ ((d&96)>>2)]; row0 = 0
  __shared__ __align__(16) float s_lds[2][SROW];   // shat exchange, skewed, dbuf
  __shared__ float m_sc[2];                        // gauge proxy max, dbuf
  __shared__ float fin[4];

  // ---- init ----
  for (int idx = tid; idx < 128 * KST; idx += NTHR) {
    int d = idx >> 7, j0 = idx & 127;
    float v = (d == 0) ? 0.0f : __expf(logD[j0 * 128 + d]);
    expD_x[d][j0 ^ ((d & 96) >> 2)] = v;
  }
  for (int idx = tid; idx < 2 * SROW; idx += NTHR) (&s_lds[0][0])[idx] = 0.0f;
  if (tid < 2) m_sc[tid] = 1.0f;

  // per-thread constants: exp(log_A) for sources [32c, 32c+32), both dests
  float aA0[16], aB0[16], aA1[16], aB1[16];
#pragma unroll
  for (int k = 0; k < 16; ++k) {
    aA0[k] = __expf(logA[(32 * c + k) * KST + jj0]);
    aB0[k] = __expf(logA[(32 * c + 16 + k) * KST + jj0]);
    aA1[k] = __expf(logA[(32 * c + k) * KST + jj1]);
    aB1[k] = __expf(logA[(32 * c + 16 + k) * KST + jj1]);
  }
  const float expD00 = __expf(logD[jj0 * 128 + 0]);
  const float expD01 = __expf(logD[jj1 * 128 + 0]);
  const float pexp0  = __expf(logpi[jj0]);
  const float pexp1  = __expf(logpi[jj1]);
  const int   saddr0 = jj0 + 8 * (jj0 >> 5);
  const int   saddr1 = jj1 + 8 * (jj1 >> 5);

  float QA0[16], QB0[16], QA1[16], QB1[16];
#pragma unroll
  for (int k = 0; k < 16; ++k) { QA0[k]=0.f; QB0[k]=0.f; QA1[k]=0.f; QB1[k]=0.f; }

  __syncthreads();  // table + buffers ready

  // e-window init for t=0 (xor-skewed cols)
  float eA0[16], eB0[16], eA1[16], eB1[16];
#pragma unroll
  for (int k = 0; k < 16; ++k) {
    int rA = (-(32 * c + k)) & 127;
    int rB = (-(32 * c + 16 + k)) & 127;
    int sA = (rA & 96) >> 2, sB = (rB & 96) >> 2;
    eA0[k] = expD_x[rA][jj0 ^ sA];
    eB0[k] = expD_x[rB][jj0 ^ sB];
    eA1[k] = expD_x[rA][jj1 ^ sA];
    eB1[k] = expD_x[rB][jj1 ^ sB];
  }

  // log_B prefetch rings (16 ahead)
  float lb0[16], lb1[16];
#pragma unroll
  for (int u = 0; u < 16; ++u) {
    lb0[u] = pB0[(size_t)u * KST];
    lb1[u] = pB1[(size_t)u * KST];
  }

  float psi0 = 1.f, psi1 = 1.f, invpsi0 = 1.f, invpsi1 = 1.f;
  float Ctot = 0.f, sk0 = 0.f, sk1 = 0.f;
  float exq0 = __expf(lb0[0]);
  float exq1 = __expf(lb1[0]);

#pragma unroll 1
  for (int t0 = 0; t0 < T_LEN; t0 += 16) {
#define STEP(U) step_body<U>(t0, c, jj0, jj1, w, L, pB0, pB1,                  \
                             QA0, QB0, QA1, QB1, aA0, aB0, aA1, aB1,           \
                             eA0, eB0, eA1, eB1, lb0, lb1,                     \
                             psi0, psi1, invpsi0, invpsi1, exq0, exq1,         \
                             Ctot, sk0, sk1, expD00, expD01, pexp0, pexp1,     \
                             saddr0, saddr1, s_lds, m_sc, expD_x)
    STEP(0);  STEP(1);  STEP(2);  STEP(3);
    STEP(4);  STEP(5);  STEP(6);  STEP(7);
    STEP(8);  STEP(9);  STEP(10); STEP(11);
    STEP(12); STEP(13); STEP(14); STEP(15);
#undef STEP
  }

  // ---- final: out[b] = Ctot + log sum_j shat[j] (each state once: c==0) ---
  float v = (c == 0) ? (sk0 + sk1) : 0.0f;
  v += __shfl_xor(v, 4);  v += __shfl_xor(v, 8);
  v += __shfl_xor(v, 16); v += __shfl_xor(v, 32);
  if (L == 0) fin[w] = v;
  __syncthreads();
  if (tid == 0) {
    float tot = fin[0] + fin[1] + fin[2] + fin[3];
    out[b] = Ctot + __logf(tot);
  }
}

extern "C" void kernel_launch(void* const* d_in, const int* in_sizes, int n_in,
                              void* d_out, int out_size, void* d_ws, size_t ws_size,
                              hipStream_t stream) {
  const float* logB  = (const float*)d_in[0];
  const float* logpi = (const float*)d_in[1];
  const float* logA  = (const float*)d_in[2];
  const float* logD  = (const float*)d_in[3];
  float* out = (float*)d_out;
  const int B = out_size;  // 32
  hipLaunchKernelGGL(hsmm_fwd_kernel, dim3(B), dim3(NTHR), 0, stream,
                     logB, logpi, logA, logD, out);
}

// Round 9
// 4273.991 us; speedup vs baseline: 1.3946x; 1.3946x over previous
//
#include <hip/hip_runtime.h>

// HSMM forward log-likelihood, B=32, T=8192, K=128, Dmax=128.
// One block per sequence (32 blocks, 512 threads = 8 waves).
// R9 = R6 (verified, absmax 0.0) with the instruction stream halved:
//   - v_pk_fma_f32 packing: ring halves (QA,QB) x (eA,eB) share one rotation
//     index; matvec (aA,aB) x (sA,sB) via interleaved shat LDS layout.
//   - gauge-lite (R8-validated): one b32 block-uniform proxy max (wave 0's
//     16 states) -- any positive uniform scalar is an exact gauge; clamp is
//     the NaN firewall. 1-step delay (deadbeat/stable).
//   - byte-offset walk for expD rotation reads ((off+512)&0xFFFF == exact
//     mod-128-row wrap), persistent base + imm offsets for s reads.
// Lane layout (R6): c = L&3 (source chunk), jl = L>>2, state jj = jl + 16w.

typedef float f32x2 __attribute__((ext_vector_type(2)));

#define T_LEN 8192
#define KST   128
#define NTHR  512
#define SROW  160   // interleaved shat row: 4 blocks x (32 data + 8 pad)

__device__ __forceinline__ void barrier_nodrain() {
  asm volatile("s_waitcnt lgkmcnt(0)\n\ts_barrier" ::: "memory");
}

template <int CTRL>
__device__ __forceinline__ float dpp_mov(float x) {
  int y = __builtin_amdgcn_update_dpp(0, __builtin_bit_cast(int, x),
                                      CTRL, 0xF, 0xF, true);
  return __builtin_bit_cast(float, y);
}
template <int CTRL>
__device__ __forceinline__ float dpp_add(float x) { return x + dpp_mov<CTRL>(x); }

__device__ __forceinline__ void pk_fma(f32x2& d, f32x2 a, f32x2 b) {
  asm("v_pk_fma_f32 %0, %1, %2, %0" : "+v"(d) : "v"(a), "v"(b));
}
__device__ __forceinline__ f32x2 pk_mul(f32x2 a, f32x2 b) {
  f32x2 d;
  asm("v_pk_mul_f32 %0, %1, %2" : "=v"(d) : "v"(a), "v"(b));
  return d;
}

template <int U>
__device__ __forceinline__ void step_body(
    int t0, int c, int jj, int w, int L,
    const float* __restrict__ pB,
    f32x2 (&qab)[16], const f32x2 (&aab)[16], f32x2 (&eab)[16],
    float (&lb)[16],
    int& offA, int& offB,
    float& psi, float& invpsi, float& exq, float& Ctot, float& s_keep,
    float expD0, float pexp, int saddr,
    float* s_flat, float* m_sc, const float* expD_flat)
{
  const int t = t0 + U;
  const float expB = exq;  // exp(logB[t,jj]) computed last step (off-path)

  // ---- issue memory early ----
  // global prefetch t+16 (stays in flight across barriers)
  int tn = t + 16; tn = (tn < T_LEN) ? tn : (T_LEN - 1);
  lb[U] = pB[(size_t)tn * KST];

  // expD rotation reads for NEXT step: byte-offset walk, exact row wrap
  offA = (offA + 512) & 0xFFFF;
  offB = (offB + 512) & 0xFFFF;
  const char* eb = reinterpret_cast<const char*>(expD_flat);
  const float neA = *reinterpret_cast<const float*>(eb + offA);
  const float neB = *reinterpret_cast<const float*>(eb + offB);

  // gauge proxy max from step t-1 (1 b32 broadcast)
  float Mp = m_sc[U & 1];

  // shat(t-1), interleaved: chunk c's 32 sources as 8 b128 (base + imms)
  const float* sp = s_flat + (U & 1) * SROW + 40 * c;
  const float4 v0 = *(const float4*)(sp + 0),  v1 = *(const float4*)(sp + 4);
  const float4 v2 = *(const float4*)(sp + 8),  v3 = *(const float4*)(sp + 12);
  const float4 v4 = *(const float4*)(sp + 16), v5 = *(const float4*)(sp + 20);
  const float4 v6 = *(const float4*)(sp + 24), v7 = *(const float4*)(sp + 28);

  // ---- duration dot: 16 pk-fma (lo: QA*eA, hi: QB*eB), 2 chains ----
  f32x2 da = pk_mul(qab[0], eab[(0 - U) & 15]);
  f32x2 db = pk_mul(qab[1], eab[(1 - U) & 15]);
#pragma unroll
  for (int k = 2; k < 16; k += 2) {
    pk_fma(da, qab[k],     eab[(k - U) & 15]);
    pk_fma(db, qab[k + 1], eab[(k + 1 - U) & 15]);
  }
  f32x2 ds2 = da + db;
  float dp = ds2.x + ds2.y;

  // ---- gauge update ----
  Mp = fminf(fmaxf(Mp, 1e-30f), 1e30f);   // exact (free gauge); NaN firewall
  const float rMp = __builtin_amdgcn_rcpf(Mp);
  Ctot += __logf(Mp);
  psi = psi * expB * rMp;

  // ---- matvec: 16 pk-fma over interleaved s pairs ----
  f32x2 ma = pk_mul(aab[0], f32x2{v0.x, v0.y});
  f32x2 mb = pk_mul(aab[1], f32x2{v0.z, v0.w});
  pk_fma(ma, aab[2],  f32x2{v1.x, v1.y});  pk_fma(mb, aab[3],  f32x2{v1.z, v1.w});
  pk_fma(ma, aab[4],  f32x2{v2.x, v2.y});  pk_fma(mb, aab[5],  f32x2{v2.z, v2.w});
  pk_fma(ma, aab[6],  f32x2{v3.x, v3.y});  pk_fma(mb, aab[7],  f32x2{v3.z, v3.w});
  pk_fma(ma, aab[8],  f32x2{v4.x, v4.y});  pk_fma(mb, aab[9],  f32x2{v4.z, v4.w});
  pk_fma(ma, aab[10], f32x2{v5.x, v5.y});  pk_fma(mb, aab[11], f32x2{v5.z, v5.w});
  pk_fma(ma, aab[12], f32x2{v6.x, v6.y});  pk_fma(mb, aab[13], f32x2{v6.z, v6.w});
  pk_fma(ma, aab[14], f32x2{v7.x, v7.y});  pk_fma(mb, aab[15], f32x2{v7.z, v7.w});
  f32x2 ms2 = ma + mb;
  float mp = ms2.x + ms2.y;

  // ---- quad reduce over chunks (lane bits 0,1) ----
  dp = dpp_add<0xB1>(dp); dp = dpp_add<0x4E>(dp);
  mp = dpp_add<0xB1>(mp); mp = dpp_add<0x4E>(mp);

  // ---- insert value + shat ----
  float Qins = mp * invpsi;
  if (U == 0) { if (t0 == 0) Qins = pexp; }
  const float s = fmaf(Qins, expD0, dp) * psi;

  // exp for NEXT step (loaded 15 steps ago -> arrived)
  exq = __expf(lb[(U + 1) & 15]);

  // ring insert: slot p = t&127 -> chunk (t>>5)&3, half bit4, reg U
  if (((t >> 5) & 3) == c) {
    if ((t >> 4) & 1) qab[U].y = Qins; else qab[U].x = Qins;
  }

  // gauge proxy: wave 0's 16 states (R6-verified DPP max chain)
  if (w == 0) {
    float sm = fmaxf(s, dpp_mov<0x141>(s));
    sm = fmaxf(sm, dpp_mov<0x140>(sm));
    sm = fmaxf(sm, dpp_mov<0x142>(sm));
    sm = fmaxf(sm, dpp_mov<0x143>(sm));
    if (L == 63) m_sc[(U + 1) & 1] = sm;
  }

  // publish shat (one lane per state), interleaved layout
  if (c == 0) s_flat[((U + 1) & 1) * SROW + saddr] = s;

  // commit expD window rotation (old values consumed above)
  eab[(15 - U) & 15] = f32x2{neA, neB};

  // gauge renorm every 16 steps: fold psi into ring, reset
  if (U == 15) {
    const f32x2 pp = {psi, psi};
#pragma unroll
    for (int k = 0; k < 16; ++k) qab[k] = pk_mul(qab[k], pp);
    psi = 1.0f;
  }
  invpsi = __builtin_amdgcn_rcpf(psi);

  s_keep = s;
  barrier_nodrain();
}

__global__ __launch_bounds__(NTHR, 1) void hsmm_fwd_kernel(
    const float* __restrict__ logB_all,
    const float* __restrict__ logpi,
    const float* __restrict__ logA,
    const float* __restrict__ logD,
    float* __restrict__ out)
{
  const int tid = threadIdx.x;
  const int L   = tid & 63;
  const int w   = tid >> 6;
  const int c   = L & 3;          // source chunk (quad lanes)
  const int jl  = L >> 2;         // 0..15
  const int jj  = jl + 16 * w;    // owned state
  const int b   = blockIdx.x;
  const float* __restrict__ pB = logB_all + (size_t)b * T_LEN * KST + jj;

  __shared__ __align__(16) float expD_t[128 * 128];  // [d*128 + j]; row 0 = 0
  __shared__ __align__(16) float s_lds[2 * SROW];    // interleaved shat, dbuf
  __shared__ float m_sc[2];                          // gauge proxy, dbuf
  __shared__ float fin[8];

  // ---- init ----
  for (int idx = tid; idx < 128 * 128; idx += NTHR) {
    int d = idx >> 7, j0 = idx & 127;
    expD_t[idx] = (d == 0) ? 0.0f : __expf(logD[j0 * 128 + d]);
  }
  for (int idx = tid; idx < 2 * SROW; idx += NTHR) s_lds[idx] = 0.0f;
  if (tid < 2) m_sc[tid] = 1.0f;

  // matvec constants: pairs (A[32c+k -> jj], A[32c+16+k -> jj])
  f32x2 aab[16];
#pragma unroll
  for (int k = 0; k < 16; ++k) {
    aab[k].x = __expf(logA[(32 * c + k) * KST + jj]);
    aab[k].y = __expf(logA[(32 * c + 16 + k) * KST + jj]);
  }
  const float expD0 = __expf(logD[jj * 128 + 0]);
  const float pexp  = __expf(logpi[jj]);
  // interleaved shat address: block jj>>5, pos 2*(jj&15) + ((jj>>4)&1)
  const int saddr = 40 * (jj >> 5) + 2 * (jj & 15) + ((jj >> 4) & 1);

  f32x2 qab[16];
#pragma unroll
  for (int k = 0; k < 16; ++k) qab[k] = f32x2{0.0f, 0.0f};

  __syncthreads();  // table + buffers ready

  // e-window init for t=0: eab[k] = (expD[(-(32c+k))&127][jj],
  //                                  expD[(-(32c+16+k))&127][jj])
  f32x2 eab[16];
#pragma unroll
  for (int k = 0; k < 16; ++k) {
    eab[k].x = expD_t[(((-(32 * c + k)) & 127) << 7) + jj];
    eab[k].y = expD_t[(((-(32 * c + 16 + k)) & 127) << 7) + jj];
  }

  // rotation byte offsets (pre-decremented; body adds 512 then reads row t+1-32c)
  int offA = ((((0 - 32 * c) & 127) << 7) + jj) << 2;
  int offB = ((((0 - 32 * c - 16) & 127) << 7) + jj) << 2;

  // log_B prefetch ring (16 ahead)
  float lb[16];
#pragma unroll
  for (int u = 0; u < 16; ++u) lb[u] = pB[(size_t)u * KST];

  float psi = 1.0f, invpsi = 1.0f, Ctot = 0.0f, s_keep = 0.0f;
  float exq = __expf(lb[0]);

#pragma unroll 1
  for (int t0 = 0; t0 < T_LEN; t0 += 16) {
#define STEP(U) step_body<U>(t0, c, jj, w, L, pB, qab, aab, eab, lb,          \
                             offA, offB, psi, invpsi, exq, Ctot, s_keep,      \
                             expD0, pexp, saddr, s_lds, m_sc, expD_t)
    STEP(0);  STEP(1);  STEP(2);  STEP(3);
    STEP(4);  STEP(5);  STEP(6);  STEP(7);
    STEP(8);  STEP(9);  STEP(10); STEP(11);
    STEP(12); STEP(13); STEP(14); STEP(15);
#undef STEP
  }

  // ---- final: out[b] = Ctot + log sum_j shat[j] (each state once: c==0) ---
  float v = (c == 0) ? s_keep : 0.0f;
  v += __shfl_xor(v, 1);  v += __shfl_xor(v, 2);
  v += __shfl_xor(v, 4);  v += __shfl_xor(v, 8);
  v += __shfl_xor(v, 16); v += __shfl_xor(v, 32);
  if (L == 0) fin[w] = v;
  __syncthreads();
  if (tid == 0) {
    float tot = 0.0f;
#pragma unroll
    for (int i = 0; i < 8; ++i) tot += fin[i];
    out[b] = Ctot + __logf(tot);
  }
}

extern "C" void kernel_launch(void* const* d_in, const int* in_sizes, int n_in,
                              void* d_out, int out_size, void* d_ws, size_t ws_size,
                              hipStream_t stream) {
  const float* logB  = (const float*)d_in[0];
  const float* logpi = (const float*)d_in[1];
  const float* logA  = (const float*)d_in[2];
  const float* logD  = (const float*)d_in[3];
  float* out = (float*)d_out;
  const int B = out_size;  // 32
  hipLaunchKernelGGL(hsmm_fwd_kernel, dim3(B), dim3(NTHR), 0, stream,
                     logB, logpi, logA, logD, out);
}

// Round 10
// 4098.287 us; speedup vs baseline: 1.4543x; 1.0429x over previous
//
#include <hip/hip_runtime.h>

// HSMM forward log-likelihood, B=32, T=8192, K=128, Dmax=128.
// One block per sequence (32 blocks, 512 threads = 8 waves, 2/SIMD).
// R10 = R9 (verified, 4274us) with LDS instructions halved:
//   8-lane groups, 2 states/thread (j, j+64), 8 source-pair chunks.
//   - matvec: 4 ds_read_b128/thread (was 8); dests paired in pk lanes via
//     op_sel source-broadcast (v_pk_fma_f32 op_sel variants).
//   - ring/e-window state-paired: dot = 16 pk; e-refresh = 1 ds_read_b64
//     (was 2 b32) from a pair-interleaved skewed expD table.
//   - shat exchange: pair-interleaved + chunk-padded layout, one
//     ds_write_b64 per group; all LDS conflict-free by construction.
// Gauge machinery (1-step proxy max, clamp, fold-every-16) = R9 verbatim.
//
// Lane layout: cc = L&7 (source chunk), g = L>>3 (dest group), wave w:
//   j0 = 8w + g (0..63), j1 = j0 + 64.
// Ring: lane cc holds slots [16cc, 16cc+16) of both states as pairs qq[16];
// e-window ee[16] rotates with renaming index (k-U)&15 (R9 machinery).

typedef float f32x2 __attribute__((ext_vector_type(2)));

#define T_LEN 8192
#define KST   128
#define NTHR  512
#define SROW  160   // shat buffer: 8 chunks x (16 data + 4 pad) floats

__device__ __forceinline__ void barrier_nodrain() {
  asm volatile("s_waitcnt lgkmcnt(0)\n\ts_barrier" ::: "memory");
}

template <int CTRL>
__device__ __forceinline__ float dpp_mov(float x) {
  int y = __builtin_amdgcn_update_dpp(0, __builtin_bit_cast(int, x),
                                      CTRL, 0xF, 0xF, true);
  return __builtin_bit_cast(float, y);
}
// butterfly add on a pair (2 dpp_mov + 1 pk add)
template <int CTRL>
__device__ __forceinline__ f32x2 dpp_addv(f32x2 x) {
  f32x2 y;
  y.x = dpp_mov<CTRL>(x.x);
  y.y = dpp_mov<CTRL>(x.y);
  return x + y;
}

__device__ __forceinline__ void pk_fma(f32x2& d, f32x2 a, f32x2 b) {
  asm("v_pk_fma_f32 %0, %1, %2, %0" : "+v"(d) : "v"(a), "v"(b));
}
// acc.lo += a.lo * b.lo; acc.hi += a.hi * b.lo   (broadcast b.lo)
__device__ __forceinline__ void pk_fma_blo(f32x2& d, f32x2 a, f32x2 b) {
  asm("v_pk_fma_f32 %0, %1, %2, %0 op_sel:[0,0,0] op_sel_hi:[1,0,1]"
      : "+v"(d) : "v"(a), "v"(b));
}
// acc.lo += a.lo * b.hi; acc.hi += a.hi * b.hi   (broadcast b.hi)
__device__ __forceinline__ void pk_fma_bhi(f32x2& d, f32x2 a, f32x2 b) {
  asm("v_pk_fma_f32 %0, %1, %2, %0 op_sel:[0,1,0] op_sel_hi:[1,1,1]"
      : "+v"(d) : "v"(a), "v"(b));
}
__device__ __forceinline__ f32x2 pk_mul(f32x2 a, f32x2 b) {
  f32x2 d;
  asm("v_pk_mul_f32 %0, %1, %2" : "=v"(d) : "v"(a), "v"(b));
  return d;
}

template <int U>
__device__ __forceinline__ void step_body(
    int t0, int cc, int w, int L, int sel, int c2, int cc16,
    const float* __restrict__ pB0, const float* __restrict__ pB1,
    f32x2 (&qq)[16], const f32x2 (&Apl)[8], const f32x2 (&Aph)[8],
    f32x2 (&ee)[16], float (&lb0)[16], float (&lb1)[16],
    int& off,
    f32x2& psi, f32x2& invpsi, f32x2& exq, float& Ctot, f32x2& skeep,
    f32x2 expD0p, f32x2 pexpp, int swaddr,
    float* s_flat, float* m_sc, const float* ep_flat)
{
  const int t = t0 + U;
  const f32x2 expB = exq;  // exp(logB[t, j0/j1]), computed last step

  // (a) prefetch logB t+16 (stays in flight across barriers)
  int tn = t + 16; tn = (tn < T_LEN) ? tn : (T_LEN - 1);
  lb0[U] = pB0[(size_t)tn * KST];
  lb1[U] = pB1[(size_t)tn * KST];

  // (b) e-window refresh read for t+1 (byte-offset walk; the column skew
  //     changes exactly at U==15 -> full recompute there)
  if (U == 15) {
    int rn = (t0 + 16 - cc16) & 127;
    int cl = (c2 + 4 * ((rn >> 4) & 7)) & 127;
    off = rn * 512 + cl * 4;
  } else {
    off = (off + 512) & 0xFFFF;
  }
  const f32x2 ne =
      *reinterpret_cast<const f32x2*>(reinterpret_cast<const char*>(ep_flat) + off);

  // (c) gauge proxy max from step t-1 (1 b32 broadcast)
  float Mp = m_sc[U & 1];

  // (d) shat(t-1): this chunk's 8 source-pairs (4 b128, conflict-free)
  const float* sp = s_flat + (U & 1) * SROW + 20 * cc;
  const float4 v0 = *(const float4*)(sp + 0),  v1 = *(const float4*)(sp + 4);
  const float4 v2 = *(const float4*)(sp + 8),  v3 = *(const float4*)(sp + 12);

  // (e) duration dot: 16 pk over state-paired ring (2 chains)
  f32x2 da = pk_mul(qq[0], ee[(0 - U) & 15]);
  f32x2 db = pk_mul(qq[1], ee[(1 - U) & 15]);
#pragma unroll
  for (int k = 2; k < 16; k += 2) {
    pk_fma(da, qq[k],     ee[(k - U) & 15]);
    pk_fma(db, qq[k + 1], ee[(k + 1 - U) & 15]);
  }
  f32x2 dp = da + db;

  // (f) gauge update (clamp = exact free gauge + NaN firewall)
  Mp = fminf(fmaxf(Mp, 1e-30f), 1e30f);
  const float rMp = __builtin_amdgcn_rcpf(Mp);
  Ctot += __logf(Mp);
  psi = pk_mul(psi, pk_mul(expB, f32x2{rMp, rMp}));

  // (g) matvec: 16 pk, dests (j0,j1) in pk lanes, source-broadcast op_sel
  f32x2 ma = {0.0f, 0.0f}, mb = {0.0f, 0.0f};
  pk_fma_blo(ma, Apl[0], f32x2{v0.x, v0.y});  pk_fma_bhi(mb, Aph[0], f32x2{v0.x, v0.y});
  pk_fma_blo(ma, Apl[1], f32x2{v0.z, v0.w});  pk_fma_bhi(mb, Aph[1], f32x2{v0.z, v0.w});
  pk_fma_blo(ma, Apl[2], f32x2{v1.x, v1.y});  pk_fma_bhi(mb, Aph[2], f32x2{v1.x, v1.y});
  pk_fma_blo(ma, Apl[3], f32x2{v1.z, v1.w});  pk_fma_bhi(mb, Aph[3], f32x2{v1.z, v1.w});
  pk_fma_blo(ma, Apl[4], f32x2{v2.x, v2.y});  pk_fma_bhi(mb, Aph[4], f32x2{v2.x, v2.y});
  pk_fma_blo(ma, Apl[5], f32x2{v2.z, v2.w});  pk_fma_bhi(mb, Aph[5], f32x2{v2.z, v2.w});
  pk_fma_blo(ma, Apl[6], f32x2{v3.x, v3.y});  pk_fma_bhi(mb, Aph[6], f32x2{v3.x, v3.y});
  pk_fma_blo(ma, Apl[7], f32x2{v3.z, v3.w});  pk_fma_bhi(mb, Aph[7], f32x2{v3.z, v3.w});
  f32x2 mp = ma + mb;

  // (h) reduce over 8 chunks (lane bits 0..2): xor1, xor2, mirror-8
  dp = dpp_addv<0xB1>(dp); dp = dpp_addv<0x4E>(dp); dp = dpp_addv<0x141>(dp);
  mp = dpp_addv<0xB1>(mp); mp = dpp_addv<0x4E>(mp); mp = dpp_addv<0x141>(mp);

  // (i) insert pair + shat pair (group-uniform)
  f32x2 Qins = pk_mul(mp, invpsi);
  if (U == 0) { if (t0 == 0) Qins = pexpp; }
  f32x2 sacc = dp;
  pk_fma(sacc, Qins, expD0p);
  const f32x2 s = pk_mul(sacc, psi);

  // (j) exp for NEXT step (loaded 15 steps ago -> arrived)
  exq.x = __expf(lb0[(U + 1) & 15]);
  exq.y = __expf(lb1[(U + 1) & 15]);

  // (k) ring insert: slot p = t&127 -> chunk sel = (t>>4)&7, reg U
  if (sel == cc) qq[U] = Qins;

  // (l) gauge proxy: wave 0's 16 states (verified DPP max chain; values
  //     are 8-lane-uniform so the mirror-8 stage is unnecessary)
  if (w == 0) {
    float sm = fmaxf(s.x, s.y);
    sm = fmaxf(sm, dpp_mov<0x140>(sm));   // row_mirror: groups within 16
    sm = fmaxf(sm, dpp_mov<0x142>(sm));   // row_bcast15
    sm = fmaxf(sm, dpp_mov<0x143>(sm));   // row_bcast31 -> lane 63
    if (L == 63) m_sc[(U + 1) & 1] = sm;
  }

  // (m) publish shat pair: one b64 per group, padded interleaved layout
  if (cc == 0)
    *reinterpret_cast<f32x2*>(s_flat + ((U + 1) & 1) * SROW + swaddr) = s;

  // (n) commit e-window rotation (old values fully consumed in (e))
  ee[(15 - U) & 15] = ne;

  // (o) gauge renorm every 16 steps: fold psi into ring, reset
  if (U == 15) {
#pragma unroll
    for (int k = 0; k < 16; ++k) qq[k] = pk_mul(qq[k], psi);
    psi = f32x2{1.0f, 1.0f};
  }
  invpsi.x = __builtin_amdgcn_rcpf(psi.x);
  invpsi.y = __builtin_amdgcn_rcpf(psi.y);

  skeep = s;
  barrier_nodrain();
}

__global__ __launch_bounds__(NTHR, 1) void hsmm_fwd_kernel(
    const float* __restrict__ logB_all,
    const float* __restrict__ logpi,
    const float* __restrict__ logA,
    const float* __restrict__ logD,
    float* __restrict__ out)
{
  const int tid = threadIdx.x;
  const int L   = tid & 63;
  const int w   = tid >> 6;
  const int cc  = L & 7;            // source chunk (8 lanes per group)
  const int g   = L >> 3;           // dest group 0..7
  const int j0  = 8 * w + g;        // state pair (j0, j0+64)
  const int j1  = j0 + 64;
  const int b   = blockIdx.x;
  const float* __restrict__ pB0 = logB_all + (size_t)b * T_LEN * KST + j0;
  const float* __restrict__ pB1 = pB0 + 64;

  // epair[d][(2j + 4*((d>>4)&7)) & 127 (+1)] = (expD[j][d], expD[j+64][d]);
  // row 0 zeroed (stale-slot kill). Skew -> conflict-free rotation reads.
  __shared__ __align__(16) float epair[128 * 128];
  __shared__ __align__(16) float s_lds[2 * SROW];  // padded interleaved shat
  __shared__ float m_sc[2];                        // gauge proxy, dbuf
  __shared__ float fin[8];

  // ---- init ----
  for (int idx = tid; idx < 128 * 128; idx += NTHR) {
    int d = idx >> 7, r = idx & 127;
    int j = r >> 1, hb = r & 1;
    int col = ((2 * j + 4 * ((d >> 4) & 7)) & 127) + hb;
    epair[(d << 7) + col] = (d == 0) ? 0.0f : __expf(logD[(j + 64 * hb) * 128 + d]);
  }
  if (tid < 2 * SROW) s_lds[tid] = 0.0f;
  if (tid < 2) m_sc[tid] = 1.0f;

  // matvec constants: chunk cc covers source pairs m = 8cc+k, k=0..7
  f32x2 Apl[8], Aph[8];
#pragma unroll
  for (int k = 0; k < 8; ++k) {
    int m = 8 * cc + k;
    Apl[k].x = __expf(logA[m * KST + j0]);
    Apl[k].y = __expf(logA[m * KST + j1]);
    Aph[k].x = __expf(logA[(m + 64) * KST + j0]);
    Aph[k].y = __expf(logA[(m + 64) * KST + j1]);
  }
  const f32x2 expD0p = {__expf(logD[j0 * 128]), __expf(logD[j1 * 128])};
  const f32x2 pexpp  = {__expf(logpi[j0]), __expf(logpi[j1])};
  const int   swaddr = 20 * w + 2 * g;   // padded interleaved write pos
  const int   c2     = 16 * w + 2 * g;   // epair column base (2*j0)
  const int   cc16   = 16 * cc;

  f32x2 qq[16];
#pragma unroll
  for (int k = 0; k < 16; ++k) qq[k] = f32x2{0.0f, 0.0f};

  __syncthreads();  // table + buffers ready

  // e-window init for t=0: ee[k] = epair row (-(16cc+k))&127, col base c2
  f32x2 ee[16];
#pragma unroll
  for (int k = 0; k < 16; ++k) {
    int rA = (-(cc16 + k)) & 127;
    int cl = (c2 + 4 * ((rA >> 4) & 7)) & 127;
    ee[k] = *reinterpret_cast<const f32x2*>(&epair[(rA << 7) + cl]);
  }

  // rotation byte offset, pre-decremented (step adds 512 -> row 1-16cc)
  int off;
  {
    int r0 = (-cc16) & 127;
    int cl = (c2 + 4 * ((r0 >> 4) & 7)) & 127;
    off = r0 * 512 + cl * 4;
  }

  // log_B prefetch rings (16 ahead)
  float lb0[16], lb1[16];
#pragma unroll
  for (int u = 0; u < 16; ++u) {
    lb0[u] = pB0[(size_t)u * KST];
    lb1[u] = pB1[(size_t)u * KST];
  }

  f32x2 psi = {1.0f, 1.0f}, invpsi = {1.0f, 1.0f};
  float Ctot = 0.0f;
  f32x2 skeep = {0.0f, 0.0f};
  f32x2 exq = {__expf(lb0[0]), __expf(lb1[0])};

#pragma unroll 1
  for (int t0 = 0; t0 < T_LEN; t0 += 16) {
    const int sel = (t0 >> 4) & 7;   // ring chunk receiving this block
#define STEP(U) step_body<U>(t0, cc, w, L, sel, c2, cc16, pB0, pB1, qq,       \
                             Apl, Aph, ee, lb0, lb1, off, psi, invpsi, exq,   \
                             Ctot, skeep, expD0p, pexpp, swaddr,              \
                             s_lds, m_sc, epair)
    STEP(0);  STEP(1);  STEP(2);  STEP(3);
    STEP(4);  STEP(5);  STEP(6);  STEP(7);
    STEP(8);  STEP(9);  STEP(10); STEP(11);
    STEP(12); STEP(13); STEP(14); STEP(15);
#undef STEP
  }

  // ---- final: out[b] = Ctot + log sum_j shat[j] (each pair once: cc==0) --
  float v = (cc == 0) ? (skeep.x + skeep.y) : 0.0f;
  v += __shfl_xor(v, 8);  v += __shfl_xor(v, 16); v += __shfl_xor(v, 32);
  if (L == 0) fin[w] = v;
  __syncthreads();
  if (tid == 0) {
    float tot = 0.0f;
#pragma unroll
    for (int i = 0; i < 8; ++i) tot += fin[i];
    out[b] = Ctot + __logf(tot);
  }
}

extern "C" void kernel_launch(void* const* d_in, const int* in_sizes, int n_in,
                              void* d_out, int out_size, void* d_ws, size_t ws_size,
                              hipStream_t stream) {
  const float* logB  = (const float*)d_in[0];
  const float* logpi = (const float*)d_in[1];
  const float* logA  = (const float*)d_in[2];
  const float* logD  = (const float*)d_in[3];
  float* out = (float*)d_out;
  const int B = out_size;  // 32
  hipLaunchKernelGGL(hsmm_fwd_kernel, dim3(B), dim3(NTHR), 0, stream,
                     logB, logpi, logA, logD, out);
}